// Round 6
// baseline (270.596 us; speedup 1.0000x reference)
//
#include <hip/hip_runtime.h>
#include <stdint.h>

// GIN conv: agg = segment_sum(val * x[col], row); h=(1+eps)x+agg;
// h=relu(h@W1+b1); h=relu(h@W2+b2); out=relu(h+bias).
// R5: R4 + the missing __syncthreads() between k_pcvt's LDS histogram
// atomics and the hist[] read feeding the scan (the R4 correctness bug).

static constexpr int NN = 100000;
static constexpr int NE = 1600000;
static constexpr int NB = 196;    // buckets of 512 rows
static constexpr int EPB = 4096;  // edges per partition block
static constexpr int PB = (NE + EPB - 1) / EPB;  // 391
static constexpr int CVB = 3125;  // cvt blocks: NN*32 float4 / 1024

typedef float f32x4 __attribute__((ext_vector_type(4)));
typedef short s16x8 __attribute__((ext_vector_type(8)));

__device__ __forceinline__ uint16_t f2bf(float f) {
  uint32_t u = __float_as_uint(f);
  u += 0x7fffu + ((u >> 16) & 1u);   // round-to-nearest-even
  return (uint16_t)(u >> 16);
}
__device__ __forceinline__ float2 bf2f(uint32_t w) {
  float2 r;
  r.x = __uint_as_float(w << 16);
  r.y = __uint_as_float(w & 0xffff0000u);
  return r;
}

// inclusive scan of per-thread v over a 1024-thread block; 3 barriers.
// wsum: LDS int[16]. ALL threads must call.
__device__ __forceinline__ int block_scan_inc(int v, int* wsum, int tid) {
  __syncthreads();  // protect wsum reuse across consecutive calls
  int lane = tid & 63, wv = tid >> 6;
  #pragma unroll
  for (int off = 1; off < 64; off <<= 1) {
    int t = __shfl_up(v, off, 64);
    if (lane >= off) v += t;
  }
  if (lane == 63) wsum[wv] = v;
  __syncthreads();
  if (wv == 0) {
    int s = (lane < 16) ? wsum[lane] : 0;
    #pragma unroll
    for (int off = 1; off < 16; off <<= 1) {
      int t = __shfl_up(s, off, 64);
      if (lane >= off) s += t;
    }
    if (lane < 16) wsum[lane] = s;
  }
  __syncthreads();
  if (wv > 0) v += wsum[wv - 1];
  return v;
}

// ------- fused: blocks [0,PB) partition edges; blocks [PB, PB+CVB) cvt x -----
__global__ __launch_bounds__(1024) void k_pcvt(const float* __restrict__ x,
                                               uint32_t* __restrict__ xb,
                                               const int* __restrict__ erow,
                                               const int* __restrict__ ecol,
                                               const float* __restrict__ eval,
                                               int2* __restrict__ part,
                                               int* __restrict__ runstart) {
  int t = threadIdx.x;
  if (blockIdx.x >= PB) {
    int i = (blockIdx.x - PB) * 1024 + t;  // i < NN*32 exactly
    float4 v = ((const float4*)x)[i];
    uint2 o;
    o.x = (uint32_t)f2bf(v.x) | ((uint32_t)f2bf(v.y) << 16);
    o.y = (uint32_t)f2bf(v.z) | ((uint32_t)f2bf(v.w) << 16);
    ((uint2*)xb)[i] = o;
    return;
  }
  __shared__ int hist[NB];
  __shared__ int cur[NB];
  __shared__ int wsum[16];
  __shared__ int2 stage[EPB];
  int base = blockIdx.x * EPB;
  int cnt = min(EPB, NE - base);

  if (t < NB) hist[t] = 0;
  __syncthreads();

  int pb[4], pk[4], pv[4];
  #pragma unroll
  for (int j = 0; j < 4; ++j) {
    int i = t + j * 1024;
    pb[j] = -1;
    if (i < cnt) {
      int e = base + i;
      int r = erow[e];
      int b = r >> 9;
      pb[j] = b;
      pk[j] = ecol[e] | ((r & 511) << 17);
      pv[j] = __float_as_int(eval[e]);
      atomicAdd(&hist[b], 1);
    }
  }
  __syncthreads();  // R5 FIX: order histogram atomics before hist[] read

  int hv = (t < NB) ? hist[t] : 0;
  int inc = block_scan_inc(hv, wsum, t);
  if (t < NB) {
    int st = inc - hv;  // exclusive
    cur[t] = st;
    runstart[blockIdx.x * (NB + 1) + t] = st;
  }
  if (t == 0) runstart[blockIdx.x * (NB + 1) + NB] = cnt;
  __syncthreads();

  #pragma unroll
  for (int j = 0; j < 4; ++j) {
    if (pb[j] >= 0) {
      int off = atomicAdd(&cur[pb[j]], 1);
      stage[off] = int2{pk[j], pv[j]};
    }
  }
  __syncthreads();

  for (int i = t; i < cnt; i += 1024) part[base + i] = stage[i];
}

// ------- bucket bases: column-sum runstart lens, exclusive scan -------------
__global__ __launch_bounds__(1024) void k_bbase(const int* __restrict__ runstart,
                                                int* __restrict__ bbase,
                                                int2* __restrict__ es_pad) {
  __shared__ int psum[4][256];
  __shared__ int wsum[16];
  int t = threadIdx.x;
  int g = t >> 8, b = t & 255;
  int acc = 0;
  if (b < NB) {
    for (int p = g; p < PB; p += 4)
      acc += runstart[p * (NB + 1) + b + 1] - runstart[p * (NB + 1) + b];
  }
  psum[g][b] = acc;
  __syncthreads();
  int v = 0;
  if (g == 0 && b < NB) v = psum[0][b] + psum[1][b] + psum[2][b] + psum[3][b];
  int inc = block_scan_inc(v, wsum, t);
  if (g == 0 && b < NB) bbase[b] = inc - v;  // exclusive: threads 0..195 in order
  if (t < 16) es_pad[t] = int2{0, 0};
}

// ------- phase 2: per-bucket CSR (one block per bucket) ---------------------
__global__ __launch_bounds__(1024) void k_bucket(const int2* __restrict__ part,
                                                 const int* __restrict__ runstart,
                                                 const int* __restrict__ bbase,
                                                 int2* __restrict__ es,
                                                 int* __restrict__ rowptr) {
  __shared__ int cum[PB + 1];
  __shared__ int rbas[PB];
  __shared__ int hist[512];
  __shared__ int rps[512];
  __shared__ int cur[512];
  __shared__ int wsum[16];
  int b = blockIdx.x, t = threadIdx.x;
  int base_out = bbase[b];

  int len = 0;
  if (t < PB) {
    int rs = runstart[t * (NB + 1) + b];
    int re = runstart[t * (NB + 1) + b + 1];
    len = re - rs;
    rbas[t] = t * EPB + rs;
  }
  int inc1 = block_scan_inc(len, wsum, t);
  if (t < PB) cum[t] = inc1 - len;
  if (t == 1023) cum[PB] = inc1;  // total
  if (t < 512) hist[t] = 0;
  __syncthreads();

  int total = cum[PB];

  // pass 1: gather edges (binary search run), histogram rows-in-bucket
  int pk[16], pv[16];
  #pragma unroll
  for (int j = 0; j < 16; ++j) {
    int s = t + j * 1024;
    pk[j] = -1;
    if (s < total) {
      int lo = 0, hi = PB;  // invariant: cum[lo] <= s < cum[hi]
      while (hi - lo > 1) {
        int mid = (lo + hi) >> 1;
        if (cum[mid] <= s) lo = mid; else hi = mid;
      }
      int2 ev = part[rbas[lo] + (s - cum[lo])];
      pk[j] = ev.x; pv[j] = ev.y;
      atomicAdd(&hist[ev.x >> 17], 1);
    }
  }
  __syncthreads();  // order histogram atomics before hist[] read
  int hv = (t < 512) ? hist[t] : 0;
  int inc2 = block_scan_inc(hv, wsum, t);
  if (t < 512) {
    int ex = inc2 - hv;
    rps[t] = ex;
    cur[t] = ex;
  }
  __syncthreads();

  if (t < 512) {
    int row = b * 512 + t;
    if (row <= NN) rowptr[row] = base_out + rps[t];
  }

  // pass 2: ticket-scatter into this bucket's contiguous es region
  #pragma unroll
  for (int j = 0; j < 16; ++j) {
    if (pk[j] >= 0) {
      int rib = pk[j] >> 17;
      int off = atomicAdd(&cur[rib], 1);
      es[base_out + off] = int2{pk[j] & 0x1FFFF, pv[j]};
    }
  }
}

// ------- aggregate: one wave per node, scalar edge stream, 16-deep ----------
__global__ __launch_bounds__(256) void k_agg(const uint32_t* __restrict__ xb,
                                             const int2* __restrict__ es,
                                             const int* __restrict__ rowptr,
                                             const float* __restrict__ eps,
                                             uint32_t* __restrict__ hb) {
  int wid = (blockIdx.x * 256 + threadIdx.x) >> 6;
  int wave = __builtin_amdgcn_readfirstlane(wid);
  int lane = threadIdx.x & 63;
  float e = 1.0f + eps[0];
  float2 h = bf2f(xb[(size_t)wave * 64 + lane]);
  h.x *= e; h.y *= e;
  int beg = __builtin_amdgcn_readfirstlane(rowptr[wave]);
  int end = __builtin_amdgcn_readfirstlane(rowptr[wave + 1]);
  for (int k = beg; k < end; k += 16) {
    int scol[16]; float sval[16];
    #pragma unroll
    for (int j = 0; j < 16; ++j) {
      int2 ev = es[k + j];  // es padded by 16 zero entries at the very end
      scol[j] = __builtin_amdgcn_readfirstlane(ev.x);
      int vb = __builtin_amdgcn_readfirstlane(ev.y);
      sval[j] = (k + j < end) ? __int_as_float(vb) : 0.0f;
    }
    uint32_t xw[16];
    #pragma unroll
    for (int j = 0; j < 16; ++j)
      xw[j] = xb[((size_t)scol[j] << 6) + lane];
    #pragma unroll
    for (int j = 0; j < 16; ++j) {
      float2 xv = bf2f(xw[j]);
      h.x = fmaf(sval[j], xv.x, h.x);
      h.y = fmaf(sval[j], xv.y, h.y);
    }
  }
  hb[(size_t)wave * 64 + lane] = (uint32_t)f2bf(h.x) | ((uint32_t)f2bf(h.y) << 16);
}

// ------- fused 2-layer MFMA MLP: 64 rows per block --------------------------
__global__ __launch_bounds__(256, 3) void k_mlp(const uint16_t* __restrict__ A,
                                                const float* __restrict__ W1,
                                                const float* __restrict__ b1,
                                                const float* __restrict__ W2,
                                                const float* __restrict__ b2,
                                                const float* __restrict__ bias,
                                                float* __restrict__ out, int nrows) {
  __shared__ uint16_t wt[128 * 136];
  __shared__ uint16_t h1[64 * 136];
  int tid = threadIdx.x;

  #pragma unroll 4
  for (int it = 0; it < 64; ++it) {
    int idx = tid + it * 256;
    wt[(idx & 127) * 136 + (idx >> 7)] = f2bf(W1[idx]);
  }
  __syncthreads();

  int wv = tid >> 6, l = tid & 63;
  int m16 = l & 15, qg = l >> 4;
  int r0 = blockIdx.x * 64 + wv * 16;
  int arow = r0 + m16;
  if (arow >= nrows) arow = nrows - 1;  // clamp; stores guarded

  f32x4 acc[8];
  #pragma unroll
  for (int n0 = 0; n0 < 8; ++n0) acc[n0] = f32x4{0.f, 0.f, 0.f, 0.f};

  #pragma unroll
  for (int k0 = 0; k0 < 128; k0 += 32) {
    s16x8 a = *(const s16x8*)(A + (size_t)arow * 128 + k0 + qg * 8);
    #pragma unroll
    for (int n0 = 0; n0 < 8; ++n0) {
      s16x8 bfr = *(const s16x8*)(&wt[(n0 * 16 + m16) * 136 + k0 + qg * 8]);
      acc[n0] = __builtin_amdgcn_mfma_f32_16x16x32_bf16(a, bfr, acc[n0], 0, 0, 0);
    }
  }

  // epilogue 1: relu(acc + b1) -> h1 LDS (bf16). C/D: col=lane&15, row=qg*4+j
  #pragma unroll
  for (int n0 = 0; n0 < 8; ++n0) {
    int col = n0 * 16 + m16;
    float bb = b1[col];
    #pragma unroll
    for (int j = 0; j < 4; ++j) {
      int lr = wv * 16 + qg * 4 + j;
      h1[lr * 136 + col] = f2bf(fmaxf(acc[n0][j] + bb, 0.0f));
    }
  }
  __syncthreads();

  #pragma unroll 4
  for (int it = 0; it < 64; ++it) {
    int idx = tid + it * 256;
    wt[(idx & 127) * 136 + (idx >> 7)] = f2bf(W2[idx]);
  }
  #pragma unroll
  for (int n0 = 0; n0 < 8; ++n0) acc[n0] = f32x4{0.f, 0.f, 0.f, 0.f};
  __syncthreads();

  #pragma unroll
  for (int k0 = 0; k0 < 128; k0 += 32) {
    s16x8 a = *(const s16x8*)(&h1[(wv * 16 + m16) * 136 + k0 + qg * 8]);
    #pragma unroll
    for (int n0 = 0; n0 < 8; ++n0) {
      s16x8 bfr = *(const s16x8*)(&wt[(n0 * 16 + m16) * 136 + k0 + qg * 8]);
      acc[n0] = __builtin_amdgcn_mfma_f32_16x16x32_bf16(a, bfr, acc[n0], 0, 0, 0);
    }
  }

  // epilogue 2: relu(relu(acc + b2) + bias) -> out (fp32)
  #pragma unroll
  for (int n0 = 0; n0 < 8; ++n0) {
    int col = n0 * 16 + m16;
    float bb = b2[col];
    float b3 = bias[col];
    #pragma unroll
    for (int j = 0; j < 4; ++j) {
      int row = r0 + qg * 4 + j;
      if (row < nrows) {
        float v = fmaxf(fmaxf(acc[n0][j] + bb, 0.0f) + b3, 0.0f);
        out[(size_t)row * 128 + col] = v;
      }
    }
  }
}

extern "C" void kernel_launch(void* const* d_in, const int* in_sizes, int n_in,
                              void* d_out, int out_size, void* d_ws, size_t ws_size,
                              hipStream_t stream) {
  const float* x    = (const float*)d_in[0];
  const int*   erow = (const int*)d_in[1];
  const int*   ecol = (const int*)d_in[2];
  const float* eval = (const float*)d_in[3];
  const float* W1   = (const float*)d_in[4];
  const float* b1   = (const float*)d_in[5];
  const float* W2   = (const float*)d_in[6];
  const float* b2   = (const float*)d_in[7];
  const float* eps  = (const float*)d_in[8];
  const float* bias = (const float*)d_in[9];

  char* w = (char*)d_ws;
  size_t off = 0;
  auto take = [&](size_t bytes) -> void* {
    void* p = w + off;
    off = (off + bytes + 255) & ~(size_t)255;
    return p;
  };
  uint32_t* xb     = (uint32_t*)take((size_t)NN * 64 * 4);   // bf16 x, packed
  uint32_t* hb     = (uint32_t*)take((size_t)NN * 64 * 4);   // bf16 h; part ALIASES
  int2*     part   = (int2*)hb;  // 12.8MB < 25.6MB; dead before k_agg writes hb
  int2*     es     = (int2*)take((size_t)(NE + 16) * 8);     // CSR (col,val)+pad
  int*      rowptr = (int*)take((size_t)(NN + 1) * 4);
  int*      runst  = (int*)take((size_t)PB * (NB + 1) * 4);
  int*      bbase  = (int*)take((size_t)(NB + 1) * 4);
  (void)ws_size;

  k_pcvt<<<PB + CVB, 1024, 0, stream>>>(x, xb, erow, ecol, eval, part, runst);
  k_bbase<<<1, 1024, 0, stream>>>(runst, bbase, es + NE);
  k_bucket<<<NB, 1024, 0, stream>>>(part, runst, bbase, es, rowptr);
  k_agg<<<(NN + 3) / 4, 256, 0, stream>>>(xb, es, rowptr, eps, hb);
  k_mlp<<<(NN + 63) / 64, 256, 0, stream>>>((const uint16_t*)hb, W1, b1, W2, b2,
                                            bias, (float*)d_out, NN);
}

// Round 7
// 269.343 us; speedup vs baseline: 1.0047x; 1.0047x over previous
//
#include <hip/hip_runtime.h>
#include <stdint.h>

// GIN conv: agg = segment_sum(val * x[col], row); h=(1+eps)x+agg;
// h=relu(h@W1+b1); h=relu(h@W2+b2); out=relu(h+bias).
// R6: k_bucket -> LDS-stage copy (no binary search), 256-row buckets;
// k_mlp -> pre-converted bf16 W (vector staging), 128 rows/block;
// k_agg -> back to 8-deep (R3-measured best).

static constexpr int NN = 100000;
static constexpr int NE = 1600000;
static constexpr int NB = 391;    // buckets of 256 rows (ceil(100000/256))
static constexpr int EPB = 4096;  // edges per partition block
static constexpr int PB = (NE + EPB - 1) / EPB;  // 391
static constexpr int CVB = 3125;  // cvt blocks: NN*32 float4 / 1024
static constexpr int SCAP = 6144; // bucket LDS stage cap (mean 4082, +32 sigma)

typedef float f32x4 __attribute__((ext_vector_type(4)));
typedef short s16x8 __attribute__((ext_vector_type(8)));

__device__ __forceinline__ uint16_t f2bf(float f) {
  uint32_t u = __float_as_uint(f);
  u += 0x7fffu + ((u >> 16) & 1u);   // round-to-nearest-even
  return (uint16_t)(u >> 16);
}
__device__ __forceinline__ float2 bf2f(uint32_t w) {
  float2 r;
  r.x = __uint_as_float(w << 16);
  r.y = __uint_as_float(w & 0xffff0000u);
  return r;
}

// inclusive scan of per-thread v over a 1024-thread block; 3 barriers.
// wsum: LDS int[16]. ALL threads must call; leading barrier protects reuse.
__device__ __forceinline__ int block_scan_inc(int v, int* wsum, int tid) {
  __syncthreads();
  int lane = tid & 63, wv = tid >> 6;
  #pragma unroll
  for (int off = 1; off < 64; off <<= 1) {
    int t = __shfl_up(v, off, 64);
    if (lane >= off) v += t;
  }
  if (lane == 63) wsum[wv] = v;
  __syncthreads();
  if (wv == 0) {
    int s = (lane < 16) ? wsum[lane] : 0;
    #pragma unroll
    for (int off = 1; off < 16; off <<= 1) {
      int t = __shfl_up(s, off, 64);
      if (lane >= off) s += t;
    }
    if (lane < 16) wsum[lane] = s;
  }
  __syncthreads();
  if (wv > 0) v += wsum[wv - 1];
  return v;
}

// ------- fused: blocks [0,PB) partition edges; blocks [PB, PB+CVB) cvt x -----
__global__ __launch_bounds__(1024) void k_pcvt(const float* __restrict__ x,
                                               uint32_t* __restrict__ xb,
                                               const int* __restrict__ erow,
                                               const int* __restrict__ ecol,
                                               const float* __restrict__ eval,
                                               int2* __restrict__ part,
                                               int* __restrict__ runstart) {
  int t = threadIdx.x;
  if (blockIdx.x >= PB) {
    int i = (blockIdx.x - PB) * 1024 + t;  // i < NN*32 exactly
    float4 v = ((const float4*)x)[i];
    uint2 o;
    o.x = (uint32_t)f2bf(v.x) | ((uint32_t)f2bf(v.y) << 16);
    o.y = (uint32_t)f2bf(v.z) | ((uint32_t)f2bf(v.w) << 16);
    ((uint2*)xb)[i] = o;
    return;
  }
  __shared__ int hist[NB];
  __shared__ int cur[NB];
  __shared__ int wsum[16];
  __shared__ int2 stage[EPB];
  int base = blockIdx.x * EPB;
  int cnt = min(EPB, NE - base);

  if (t < NB) hist[t] = 0;
  __syncthreads();

  int pb[4], pk[4], pv[4];
  #pragma unroll
  for (int j = 0; j < 4; ++j) {
    int i = t + j * 1024;
    pb[j] = -1;
    if (i < cnt) {
      int e = base + i;
      int r = erow[e];
      int b = r >> 8;                       // 256-row buckets
      pb[j] = b;
      pk[j] = ecol[e] | ((r & 255) << 17);
      pv[j] = __float_as_int(eval[e]);
      atomicAdd(&hist[b], 1);
    }
  }
  __syncthreads();  // order histogram atomics before hist[] read

  int hv = (t < NB) ? hist[t] : 0;
  int inc = block_scan_inc(hv, wsum, t);
  if (t < NB) {
    int st = inc - hv;  // exclusive
    cur[t] = st;
    runstart[blockIdx.x * (NB + 1) + t] = st;
  }
  if (t == 0) runstart[blockIdx.x * (NB + 1) + NB] = cnt;
  __syncthreads();

  #pragma unroll
  for (int j = 0; j < 4; ++j) {
    if (pb[j] >= 0) {
      int off = atomicAdd(&cur[pb[j]], 1);
      stage[off] = int2{pk[j], pv[j]};
    }
  }
  __syncthreads();

  for (int i = t; i < cnt; i += 1024) part[base + i] = stage[i];
}

// ------- aux: block 0 = bucket bases + es pad; blocks 1..8 = W -> bf16^T ----
__global__ __launch_bounds__(1024) void k_aux(const int* __restrict__ runstart,
                                              int* __restrict__ bbase,
                                              int2* __restrict__ es_pad,
                                              const float* __restrict__ W1,
                                              const float* __restrict__ W2,
                                              uint16_t* __restrict__ wtg) {
  int t = threadIdx.x;
  if (blockIdx.x > 0) {
    int base = (blockIdx.x - 1) * 4096;
    #pragma unroll
    for (int j = 0; j < 4; ++j) {
      int idx = base + j * 1024 + t;   // 0..32767 over [l][n][k]
      int l = idx >> 14, r = idx & 16383;
      int n = r >> 7, k = r & 127;
      const float* W = l ? W2 : W1;
      wtg[idx] = f2bf(W[k * 128 + n]);
    }
    return;
  }
  __shared__ int psum[2][512];
  __shared__ int wsum[16];
  int g = t >> 9, c = t & 511;
  int acc = 0;
  if (c < NB) {
    for (int p = g; p < PB; p += 2)
      acc += runstart[p * (NB + 1) + c + 1] - runstart[p * (NB + 1) + c];
  }
  psum[g][c] = acc;
  __syncthreads();
  int v = (t < NB) ? psum[0][t] + psum[1][t] : 0;
  int inc = block_scan_inc(v, wsum, t);
  if (t < NB) bbase[t] = inc - v;  // exclusive
  if (t < 16) es_pad[t] = int2{0, 0};
}

// ------- phase 2: per-bucket CSR via LDS stage (no binary search) -----------
__global__ __launch_bounds__(1024) void k_bucket(const int2* __restrict__ part,
                                                 const int* __restrict__ runstart,
                                                 const int* __restrict__ bbase,
                                                 int2* __restrict__ es,
                                                 int* __restrict__ rowptr) {
  __shared__ int cum[PB + 1];
  __shared__ int rbas[PB];
  __shared__ int hist[256];
  __shared__ int rps[256];
  __shared__ int cur[256];
  __shared__ int wsum[16];
  __shared__ int2 stage[SCAP];
  int b = blockIdx.x, t = threadIdx.x;
  int base_out = bbase[b];

  int len = 0;
  if (t < PB) {
    int rs = runstart[t * (NB + 1) + b];
    int re = runstart[t * (NB + 1) + b + 1];
    len = re - rs;
    rbas[t] = t * EPB + rs;
  }
  int inc1 = block_scan_inc(len, wsum, t);
  int mystart = inc1 - len;
  if (t == 1023) cum[PB] = inc1;  // total
  if (t < 256) hist[t] = 0;
  __syncthreads();

  // copy run t -> stage[mystart..): contiguous global reads, L2-hot
  if (t < PB) {
    int rb = rbas[t];
    for (int i = 0; i < len; ++i) {
      int d = mystart + i;
      if (d < SCAP) stage[d] = part[rb + i];
    }
  }
  __syncthreads();

  int total = min(cum[PB], SCAP);

  // pass 1: histogram rows-in-bucket from stage
  for (int i = t; i < total; i += 1024)
    atomicAdd(&hist[stage[i].x >> 17], 1);
  __syncthreads();  // order histogram atomics before hist[] read

  int hv = (t < 256) ? hist[t] : 0;
  int inc2 = block_scan_inc(hv, wsum, t);
  if (t < 256) {
    int ex = inc2 - hv;
    rps[t] = ex;
    cur[t] = ex;
  }
  __syncthreads();

  if (t < 256) {
    int row = b * 256 + t;
    if (row <= NN) rowptr[row] = base_out + rps[t];
  }

  // pass 2: ticket-scatter stage -> es (writes confined to one 48KB region)
  for (int i = t; i < total; i += 1024) {
    int2 ev = stage[i];
    int rib = ev.x >> 17;
    int off = atomicAdd(&cur[rib], 1);
    es[base_out + off] = int2{ev.x & 0x1FFFF, ev.y};
  }
}

// ------- aggregate: one wave per node, scalar edge stream, 8-deep -----------
__global__ __launch_bounds__(256) void k_agg(const uint32_t* __restrict__ xb,
                                             const int2* __restrict__ es,
                                             const int* __restrict__ rowptr,
                                             const float* __restrict__ eps,
                                             uint32_t* __restrict__ hb) {
  int wid = (blockIdx.x * 256 + threadIdx.x) >> 6;
  int wave = __builtin_amdgcn_readfirstlane(wid);
  int lane = threadIdx.x & 63;
  float e = 1.0f + eps[0];
  float2 h = bf2f(xb[(size_t)wave * 64 + lane]);
  h.x *= e; h.y *= e;
  int beg = __builtin_amdgcn_readfirstlane(rowptr[wave]);
  int end = __builtin_amdgcn_readfirstlane(rowptr[wave + 1]);
  for (int k = beg; k < end; k += 8) {
    int scol[8]; float sval[8];
    #pragma unroll
    for (int j = 0; j < 8; ++j) {
      int2 ev = es[k + j];  // es padded by 16 zero entries at the very end
      scol[j] = __builtin_amdgcn_readfirstlane(ev.x);
      int vb = __builtin_amdgcn_readfirstlane(ev.y);
      sval[j] = (k + j < end) ? __int_as_float(vb) : 0.0f;
    }
    uint32_t xw[8];
    #pragma unroll
    for (int j = 0; j < 8; ++j)
      xw[j] = xb[((size_t)scol[j] << 6) + lane];
    #pragma unroll
    for (int j = 0; j < 8; ++j) {
      float2 xv = bf2f(xw[j]);
      h.x = fmaf(sval[j], xv.x, h.x);
      h.y = fmaf(sval[j], xv.y, h.y);
    }
  }
  hb[(size_t)wave * 64 + lane] = (uint32_t)f2bf(h.x) | ((uint32_t)f2bf(h.y) << 16);
}

// ------- fused 2-layer MFMA MLP: 128 rows/block, pre-converted bf16 W -------
__global__ __launch_bounds__(256, 2) void k_mlp(const uint16_t* __restrict__ A,
                                                const uint16_t* __restrict__ wtg,
                                                const float* __restrict__ b1,
                                                const float* __restrict__ b2,
                                                const float* __restrict__ bias,
                                                float* __restrict__ out, int nrows) {
  __shared__ uint16_t wt[128 * 136];
  __shared__ uint16_t h1[128 * 136];
  int tid = threadIdx.x;

  // stage W1^T (bf16): 2048 uint4s, fully coalesced
  const uint4* wsrc = (const uint4*)wtg;
  #pragma unroll
  for (int it = 0; it < 8; ++it) {
    int idx = tid + it * 256;
    int n = idx >> 4, kq = idx & 15;
    *(uint4*)&wt[n * 136 + kq * 8] = wsrc[idx];
  }
  __syncthreads();

  int wv = tid >> 6, l = tid & 63;
  int m16 = l & 15, qg = l >> 4;
  int r0 = blockIdx.x * 128 + wv * 32;  // wave's 32-row stripe (2 m-tiles)

  int arow[2];
  #pragma unroll
  for (int mt = 0; mt < 2; ++mt) {
    int r = r0 + mt * 16 + m16;
    arow[mt] = (r < nrows) ? r : (nrows - 1);  // clamp; stores guarded
  }

  f32x4 acc[2][8];
  #pragma unroll
  for (int mt = 0; mt < 2; ++mt)
    #pragma unroll
    for (int n0 = 0; n0 < 8; ++n0) acc[mt][n0] = f32x4{0.f, 0.f, 0.f, 0.f};

  #pragma unroll
  for (int k0 = 0; k0 < 128; k0 += 32) {
    s16x8 a[2];
    #pragma unroll
    for (int mt = 0; mt < 2; ++mt)
      a[mt] = *(const s16x8*)(A + (size_t)arow[mt] * 128 + k0 + qg * 8);
    #pragma unroll
    for (int n0 = 0; n0 < 8; ++n0) {
      s16x8 bfr = *(const s16x8*)(&wt[(n0 * 16 + m16) * 136 + k0 + qg * 8]);
      #pragma unroll
      for (int mt = 0; mt < 2; ++mt)
        acc[mt][n0] = __builtin_amdgcn_mfma_f32_16x16x32_bf16(a[mt], bfr, acc[mt][n0], 0, 0, 0);
    }
  }

  // epilogue 1: relu(acc + b1) -> h1 LDS. C/D: col=lane&15, row=qg*4+j
  #pragma unroll
  for (int mt = 0; mt < 2; ++mt) {
    #pragma unroll
    for (int n0 = 0; n0 < 8; ++n0) {
      int col = n0 * 16 + m16;
      float bb = b1[col];
      #pragma unroll
      for (int j = 0; j < 4; ++j) {
        int lr = wv * 32 + mt * 16 + qg * 4 + j;
        h1[lr * 136 + col] = f2bf(fmaxf(acc[mt][n0][j] + bb, 0.0f));
      }
    }
  }
  __syncthreads();

  // stage W2^T
  #pragma unroll
  for (int it = 0; it < 8; ++it) {
    int idx = tid + it * 256;
    int n = idx >> 4, kq = idx & 15;
    *(uint4*)&wt[n * 136 + kq * 8] = wsrc[2048 + idx];
  }
  #pragma unroll
  for (int mt = 0; mt < 2; ++mt)
    #pragma unroll
    for (int n0 = 0; n0 < 8; ++n0) acc[mt][n0] = f32x4{0.f, 0.f, 0.f, 0.f};
  __syncthreads();

  #pragma unroll
  for (int k0 = 0; k0 < 128; k0 += 32) {
    s16x8 a[2];
    #pragma unroll
    for (int mt = 0; mt < 2; ++mt)
      a[mt] = *(const s16x8*)(&h1[(wv * 32 + mt * 16 + m16) * 136 + k0 + qg * 8]);
    #pragma unroll
    for (int n0 = 0; n0 < 8; ++n0) {
      s16x8 bfr = *(const s16x8*)(&wt[(n0 * 16 + m16) * 136 + k0 + qg * 8]);
      #pragma unroll
      for (int mt = 0; mt < 2; ++mt)
        acc[mt][n0] = __builtin_amdgcn_mfma_f32_16x16x32_bf16(a[mt], bfr, acc[mt][n0], 0, 0, 0);
    }
  }

  // epilogue 2: relu(relu(acc + b2) + bias) -> out (fp32)
  #pragma unroll
  for (int mt = 0; mt < 2; ++mt) {
    #pragma unroll
    for (int n0 = 0; n0 < 8; ++n0) {
      int col = n0 * 16 + m16;
      float bb = b2[col];
      float b3 = bias[col];
      #pragma unroll
      for (int j = 0; j < 4; ++j) {
        int row = r0 + mt * 16 + qg * 4 + j;
        if (row < nrows) {
          float v = fmaxf(fmaxf(acc[mt][n0][j] + bb, 0.0f) + b3, 0.0f);
          out[(size_t)row * 128 + col] = v;
        }
      }
    }
  }
}

extern "C" void kernel_launch(void* const* d_in, const int* in_sizes, int n_in,
                              void* d_out, int out_size, void* d_ws, size_t ws_size,
                              hipStream_t stream) {
  const float* x    = (const float*)d_in[0];
  const int*   erow = (const int*)d_in[1];
  const int*   ecol = (const int*)d_in[2];
  const float* eval = (const float*)d_in[3];
  const float* W1   = (const float*)d_in[4];
  const float* b1   = (const float*)d_in[5];
  const float* W2   = (const float*)d_in[6];
  const float* b2   = (const float*)d_in[7];
  const float* eps  = (const float*)d_in[8];
  const float* bias = (const float*)d_in[9];

  char* w = (char*)d_ws;
  size_t off = 0;
  auto take = [&](size_t bytes) -> void* {
    void* p = w + off;
    off = (off + bytes + 255) & ~(size_t)255;
    return p;
  };
  uint32_t* xb     = (uint32_t*)take((size_t)NN * 64 * 4);   // bf16 x, packed
  uint32_t* hb     = (uint32_t*)take((size_t)NN * 64 * 4);   // bf16 h; part ALIASES
  int2*     part   = (int2*)hb;  // 12.8MB < 25.6MB; dead before k_agg writes hb
  int2*     es     = (int2*)take((size_t)(NE + 16) * 8);     // CSR (col,val)+pad
  int*      rowptr = (int*)take((size_t)(NN + 1) * 4);
  int*      runst  = (int*)take((size_t)PB * (NB + 1) * 4);
  int*      bbase  = (int*)take((size_t)(NB + 1) * 4);
  uint16_t* wtg    = (uint16_t*)take(32768 * 2);             // bf16 W1^T,W2^T
  (void)ws_size;

  k_pcvt<<<PB + CVB, 1024, 0, stream>>>(x, xb, erow, ecol, eval, part, runst);
  k_aux<<<9, 1024, 0, stream>>>(runst, bbase, es + NE, W1, W2, wtg);
  k_bucket<<<NB, 1024, 0, stream>>>(part, runst, bbase, es, rowptr);
  k_agg<<<(NN + 3) / 4, 256, 0, stream>>>(xb, es, rowptr, eps, hb);
  k_mlp<<<(NN + 127) / 128, 256, 0, stream>>>((const uint16_t*)hb, wtg, b1, b2,
                                              bias, (float*)d_out, NN);
}